// Round 8
// baseline (475.023 us; speedup 1.0000x reference)
//
#include <hip/hip_runtime.h>

// VMD (Variational Mode Decomposition) for x: (16, 8192, 4) f32.
// B=16, C=4, T=8192, T2=16384, K=4, ALPHA=2000, TAU=0, 20 iterations.
// TAU=0 => lam == 0. Negative half stays 0 => iterate on 8192 positive bins.
//
// R8: scale the issue-bound iteration across 4x more CUs.
//  - Forward: grid=256, 4 blocks per channel. Each block redundantly computes
//    the same 8192-pt half-size FFT (no communication), then iterates on its
//    2048-bin quarter (2 bins/thread, U in f32 - no f16 pack).
//  - Per-iteration cross-block reduction: 8x atomicAdd into iteration-indexed
//    global slots + arrive counter + acquire spin w/ s_sleep. Slots zeroed by
//    hipMemsetAsync (capture-safe). Deadlock-safe: grid == CU count, and LDS/
//    waves/VGPR all allow >=2 blocks/CU, so all 256 blocks are resident.
//  - Inverse/mean unchanged from R7 (padded radix-4).

#define HALF      8192
#define NH        8192        // half-size FFT length
#define NTHREADS  1024
#define KMODES    4
#define NITERS    20
#define ALPHA_F   2000.0f

typedef float v2f __attribute__((ext_vector_type(2)));

__device__ __forceinline__ unsigned bitrev13(unsigned x) { return __brev(x) >> 19; }
__device__ __forceinline__ int pidx(int i) { return i + (i >> 4); }   // LDS pad

template <int CTRL>
__device__ __forceinline__ float dpp_add_step(float v) {
    int r = __builtin_amdgcn_update_dpp(0, __float_as_int(v), CTRL, 0xf, 0xf, true);
    return v + __int_as_float(r);
}
// Full-wave (64-lane) sum; result valid in lane 63.
__device__ __forceinline__ float wave64_sum(float v) {
    v = dpp_add_step<0x111>(v);   // row_shr:1
    v = dpp_add_step<0x112>(v);   // row_shr:2
    v = dpp_add_step<0x114>(v);   // row_shr:4
    v = dpp_add_step<0x118>(v);   // row_shr:8
    v = dpp_add_step<0x142>(v);   // row_bcast:15
    v = dpp_add_step<0x143>(v);   // row_bcast:31 -> lane63 = wave sum
    return v;
}

__device__ __forceinline__ float2 cmul(float2 a, float wr, float wi) {
    return make_float2(a.x * wr - a.y * wi, a.x * wi + a.y * wr);
}

// One radix-4 pass = two fused radix-2 DIF stages.
template <bool INV>
__device__ __forceinline__ void fft_pass4(float2* A, int tid, int s) {
    const int   log2hh = 11 - 2 * s;
    const int   hh     = 1 << log2hh;                       // h/2
    const float inv2h  = (float)(1 << (2 * s)) * (1.0f / 8192.0f);  // 1/(2h)
    #pragma unroll
    for (int u = 0; u < 2; ++u) {
        int gid = tid + u * NTHREADS;            // group id, 2048 total
        int j   = gid & (hh - 1);
        int blk = gid >> log2hh;
        int i0  = (blk << (log2hh + 2)) + j;     // blk*2h + j
        int i1  = i0 + hh;
        int i2  = i0 + 2 * hh;
        int i3  = i0 + 3 * hh;
        float2 a = A[pidx(i0)], b = A[pidx(i1)];
        float2 c = A[pidx(i2)], d = A[pidx(i3)];
        float rev = (float)j * inv2h;
        float w1r = __builtin_amdgcn_cosf(rev);
        float w1i = INV ?  __builtin_amdgcn_sinf(rev)
                        : -__builtin_amdgcn_sinf(rev);
        float2 ac = make_float2(a.x - c.x, a.y - c.y);
        float2 bd = make_float2(b.x - d.x, b.y - d.y);
        float2 t0 = make_float2(a.x + c.x, a.y + c.y);
        float2 t2 = make_float2(b.x + d.x, b.y + d.y);
        float2 t1 = cmul(ac, w1r, w1i);
        float2 t3;
        if (INV) { // W2 = +i*W1
            t3 = make_float2(-bd.x * w1i - bd.y * w1r, bd.x * w1r - bd.y * w1i);
        } else {   // W2 = -i*W1
            t3 = make_float2( bd.x * w1i + bd.y * w1r, bd.y * w1i - bd.x * w1r);
        }
        float vr = w1r * w1r - w1i * w1i;
        float vi = 2.0f * w1r * w1i;
        float2 s0 = make_float2(t0.x + t2.x, t0.y + t2.y);
        float2 s1 = cmul(make_float2(t0.x - t2.x, t0.y - t2.y), vr, vi);
        float2 s2 = make_float2(t1.x + t3.x, t1.y + t3.y);
        float2 s3 = cmul(make_float2(t1.x - t3.x, t1.y - t3.y), vr, vi);
        A[pidx(i0)] = s0;
        A[pidx(i1)] = s1;
        A[pidx(i2)] = s2;
        A[pidx(i3)] = s3;
    }
}

// Final radix-2 stage (h=1): pairs (2t, 2t+1), twiddle = 1.
__device__ __forceinline__ void fft_last2(float2* A, int tid) {
    #pragma unroll
    for (int u = 0; u < 4; ++u) {
        int t  = tid + u * NTHREADS;
        int i0 = 2 * t, i1 = 2 * t + 1;
        float2 a = A[pidx(i0)], b = A[pidx(i1)];
        A[pidx(i0)] = make_float2(a.x + b.x, a.y + b.y);
        A[pidx(i1)] = make_float2(a.x - b.x, a.y - b.y);
    }
}

// time-domain mirror extension: f[i], i in [0,16384)
__device__ __forceinline__ int mirror_t(int i) {
    if (i < 4096)       return 4095 - i;
    else if (i < 12288) return i - 4096;
    else                return 20479 - i;
}

// ---------------------------------------------------------------------------
// Kernel 1: 4 blocks per channel. Redundant half-size real-FFT, then 20 VMD
// iterations on this block's 2048-bin quarter with cross-block reduction.
// ---------------------------------------------------------------------------
__global__ __launch_bounds__(NTHREADS) void vmd_forward_iter(
    const float* __restrict__ x, float2* __restrict__ ws_u,
    float* __restrict__ ws_omega, float* __restrict__ gsum,
    unsigned* __restrict__ arrive)
{
    __shared__ float2 A[NH + (NH >> 4)];   // padded, ~68 KB
    const int tid = threadIdx.x;
    const int bid = blockIdx.x;
    const int ch  = bid >> 2;            // channel = b*4 + c
    const int q   = bid & 3;             // quarter
    const int b   = ch >> 2, c = ch & 3;
    const float* xb = x + (size_t)b * 8192 * 4 + c;   // x[b, t, c], stride 4

    // z[m] = f[2m] + i f[2m+1]
    for (int m = tid; m < NH; m += NTHREADS) {
        float re = xb[(size_t)mirror_t(2 * m) * 4];
        float im = xb[(size_t)mirror_t(2 * m + 1) * 4];
        A[pidx(m)] = make_float2(re, im);
    }
    __syncthreads();

    // 8192-pt forward FFT: 6 radix-4 passes + 1 radix-2 stage; bit-reversed out.
    for (int s = 0; s < 6; ++s) {
        fft_pass4<false>(A, tid, s);
        __syncthreads();
    }
    fft_last2(A, tid);
    __syncthreads();

    // Untangle only my quarter: bins j = q*2048 + tid + u*1024, u=0,1.
    v2f R[2];
    #pragma unroll
    for (int u = 0; u < 2; ++u) {
        int j  = q * 2048 + tid + u * NTHREADS;
        float2 z1 = A[pidx((int)bitrev13((unsigned)j))];
        float2 z2 = A[pidx((int)bitrev13((unsigned)((NH - j) & (NH - 1))))];
        float ex = 0.5f * (z1.x + z2.x);
        float ey = 0.5f * (z1.y - z2.y);
        float dx = 0.5f * (z1.x - z2.x);
        float dy = 0.5f * (z1.y + z2.y);
        // O = (dy, -dx); w = e^{-2*pi*i*j/16384}
        float rev = (float)j * (1.0f / 16384.0f);
        float wr = __builtin_amdgcn_cosf(rev);
        float wi = -__builtin_amdgcn_sinf(rev);
        R[u].x = ex + wr * dy + wi * dx;
        R[u].y = ey + wi * dy - wr * dx;
    }
    __syncthreads();   // LDS now reusable as reduction scratch

    v2f U[KMODES][2];
    #pragma unroll
    for (int u = 0; u < 2; ++u)
        #pragma unroll
        for (int k = 0; k < KMODES; ++k) { U[k][u].x = 0.f; U[k][u].y = 0.f; }

    const float f0 = (float)(q * 2048 + tid) * (1.0f / 16384.0f);
    float omg[KMODES] = {0.0f, 0.125f, 0.25f, 0.375f};  // 0.5*k/K

    float* red = (float*)A;   // [16 waves][8] partials; [128..135] totals
    const int lane = tid & 63, wid = tid >> 6;

    for (int it = 0; it < NITERS; ++it) {
        float num[KMODES], den[KMODES];
        #pragma unroll
        for (int k = 0; k < KMODES; ++k) {
            float nk = 0.f, dk = 0.f;
            const float ok = omg[k];
            #pragma unroll
            for (int u = 0; u < 2; ++u) {
                float fru = f0 + (float)u * 0.0625f;
                float d   = fru - ok;
                float dnm = fmaf(ALPHA_F * d, d, 1.0f);
                float rcp = __builtin_amdgcn_rcpf(dnm);
                v2f nm = R[u] + U[k][u];      // numerator = R + U_k
                v2f un = nm * rcp;
                R[u]   = nm - un;
                U[k][u] = un;
                float p = fmaf(un.x, un.x, un.y * un.y);
                nk = fmaf(fru, p, nk);
                dk += p;
            }
            num[k] = nk; den[k] = dk;
        }
        // Stage 1: DPP wave sums, lane63 writes partials.
        #pragma unroll
        for (int m = 0; m < KMODES; ++m) {
            num[m] = wave64_sum(num[m]);
            den[m] = wave64_sum(den[m]);
        }
        if (lane == 63) {
            float4* r4 = (float4*)&red[wid * 8];
            r4[0] = make_float4(num[0], num[1], num[2], num[3]);
            r4[1] = make_float4(den[0], den[1], den[2], den[3]);
        }
        __syncthreads();
        // Stage 2: 8 threads sum 16 wave-partials, atomicAdd to global slot.
        const int slot = (ch * NITERS + it) * 8;
        if (tid < 8) {
            float s = 0.f;
            #pragma unroll
            for (int w = 0; w < 16; ++w) s += red[w * 8 + tid];
            atomicAdd(&gsum[slot + tid], s);   // device-scope by default
        }
        __syncthreads();   // drains the atomics (vmcnt) before arrive
        if (tid == 0) {
            __threadfence();
            __hip_atomic_fetch_add(&arrive[ch * NITERS + it], 1u,
                                   __ATOMIC_ACQ_REL, __HIP_MEMORY_SCOPE_AGENT);
            while (__hip_atomic_load(&arrive[ch * NITERS + it],
                                     __ATOMIC_ACQUIRE, __HIP_MEMORY_SCOPE_AGENT) < 4u)
                __builtin_amdgcn_s_sleep(1);
        }
        __syncthreads();
        if (tid < 8)
            red[128 + tid] = __hip_atomic_load(&gsum[slot + tid],
                                               __ATOMIC_ACQUIRE,
                                               __HIP_MEMORY_SCOPE_AGENT);
        __syncthreads();
        {
            const float4 nv = *(const float4*)&red[128];
            const float4 dv = *(const float4*)&red[132];
            omg[0] = nv.x * __builtin_amdgcn_rcpf(dv.x);
            omg[1] = nv.y * __builtin_amdgcn_rcpf(dv.y);
            omg[2] = nv.z * __builtin_amdgcn_rcpf(dv.z);
            omg[3] = nv.w * __builtin_amdgcn_rcpf(dv.w);
        }
        // next iter writes red[0..127] (disjoint from 128..135) — safe.
    }

    // Write my quarter of final u_hat; q==0 writes omega.
    #pragma unroll
    for (int k = 0; k < KMODES; ++k) {
        float2* dst = ws_u + (size_t)(ch * KMODES + k) * HALF;
        #pragma unroll
        for (int u = 0; u < 2; ++u) {
            int j = q * 2048 + tid + u * NTHREADS;
            dst[j] = make_float2(U[k][u].x, U[k][u].y);
        }
    }
    if (q == 0 && tid < KMODES) ws_omega[ch * KMODES + tid] = omg[tid];
}

// ---------------------------------------------------------------------------
// Kernel 2: per (channel,mode) half-size real iFFT; middle T real samples.
// Full spectrum (verified R1): G[0]=conj(p[0]); G[j]=p[j] (1<=j<8192);
// G[8192]=conj(p[8191]); G[16384-j]=conj(p[j]).
// Half-size: E[j]=(G[j]+G[j+8192])/2, D=(G[j]-G[j+8192])/2,
//   O[j]=D*e^{+2*pi*i*j/16384}, Z=E+i*O, z=iFFT_8192(Z),
//   x[2m]=Re z[m], x[2m+1]=Im z[m].
// ---------------------------------------------------------------------------
__global__ __launch_bounds__(NTHREADS) void vmd_inverse(
    const float2* __restrict__ ws_u, float* __restrict__ out)
{
    __shared__ float2 A[NH + (NH >> 4)];
    const int tid = threadIdx.x;
    const int bid = blockIdx.x;             // ch*4 + k
    const float2* pos = ws_u + (size_t)bid * HALF;

    for (int j = tid; j < NH; j += NTHREADS) {
        float2 gj, gh;
        if (j == 0) {
            float2 p0 = pos[0], pl = pos[HALF - 1];
            gj = make_float2(p0.x, -p0.y);       // G[0]    = conj(p[0])
            gh = make_float2(pl.x, -pl.y);       // G[8192] = conj(p[8191])
        } else {
            gj = pos[j];                          // G[j]
            float2 q = pos[HALF - j];             // G[j+8192] = conj(p[8192-j])
            gh = make_float2(q.x, -q.y);
        }
        float ex = 0.5f * (gj.x + gh.x), ey = 0.5f * (gj.y + gh.y);
        float dx = 0.5f * (gj.x - gh.x), dy = 0.5f * (gj.y - gh.y);
        float rev = (float)j * (1.0f / 16384.0f);
        float wr = __builtin_amdgcn_cosf(rev);
        float wi = __builtin_amdgcn_sinf(rev);    // e^{+2*pi*i*rev}
        float ox = dx * wr - dy * wi;
        float oy = dx * wi + dy * wr;
        A[pidx(j)] = make_float2(ex - oy, ey + ox);   // Z = E + i*O
    }
    __syncthreads();

    // 8192-pt inverse FFT: 6 radix-4 passes + 1 radix-2 stage; bit-reversed out.
    for (int s = 0; s < 6; ++s) {
        fft_pass4<true>(A, tid, s);
        __syncthreads();
    }
    fft_last2(A, tid);
    __syncthreads();

    // Keep n in [4096,12288): m in [2048,6144). x[2m]=Re z, x[2m+1]=Im z.
    const int ch = bid >> 2, k = bid & 3;
    const int b  = ch >> 2,  c = ch & 3;
    float* outp = out + (size_t)(b * 4 + k) * 8192 * 4 + c;
    for (int m = 2048 + tid; m < 6144; m += NTHREADS) {
        float2 z = A[pidx((int)bitrev13((unsigned)m))];
        int t0 = 2 * m - 4096;
        outp[(size_t)t0 * 4]       = z.x * (1.0f / 8192.0f);
        outp[(size_t)(t0 + 1) * 4] = z.y * (1.0f / 8192.0f);
    }
}

// ---------------------------------------------------------------------------
// Kernel 3: omega_b[b,k] = mean_c omega[b,c,k]
// ---------------------------------------------------------------------------
__global__ void omega_mean(const float* __restrict__ ws_omega,
                           float* __restrict__ out_omega)
{
    int i = threadIdx.x;                 // b*4 + k, 64 total
    if (i < 64) {
        int b = i >> 2, k = i & 3;
        float s = 0.f;
        #pragma unroll
        for (int c = 0; c < 4; ++c) s += ws_omega[(b * 4 + c) * 4 + k];
        out_omega[i] = 0.25f * s;
    }
}

extern "C" void kernel_launch(void* const* d_in, const int* in_sizes, int n_in,
                              void* d_out, int out_size, void* d_ws, size_t ws_size,
                              hipStream_t stream)
{
    (void)in_sizes; (void)n_in; (void)out_size; (void)ws_size;
    const float* x = (const float*)d_in[0];
    float* out = (float*)d_out;

    char* ws = (char*)d_ws;
    float2*   ws_u     = (float2*)ws;                       // 16 MB
    float*    ws_omega = (float*)(ws + 16777216);           // 1 KB
    float*    gsum     = (float*)(ws + 16781312);           // 64*20*8 f32 = 40 KB
    unsigned* arrive   = (unsigned*)(ws + 16781312 + 40960);// 64*20 u32 = 5 KB
    // Zero the sync area (gsum + arrive). Async memset is graph-capture-safe.
    hipMemsetAsync(ws + 16781312, 0, 46080, stream);

    vmd_forward_iter<<<256, NTHREADS, 0, stream>>>(x, ws_u, ws_omega, gsum, arrive);
    vmd_inverse<<<256, NTHREADS, 0, stream>>>(ws_u, out);
    omega_mean<<<1, 64, 0, stream>>>(ws_omega, out + 2097152);
}

// Round 9
// 174.268 us; speedup vs baseline: 2.7258x; 2.7258x over previous
//
#include <hip/hip_runtime.h>

// VMD (Variational Mode Decomposition) for x: (16, 8192, 4) f32.
// B=16, C=4, T=8192, T2=16384, K=4, ALPHA=2000, TAU=0, 20 iterations.
// TAU=0 => lam == 0. Negative half stays 0 => iterate on 8192 positive bins.
//
// R9: revert forward to R7 (R8's cross-block sync spilled state: VGPR 24,
// WRITE 102MB, 412us). Attack the ~71us non-forward residual instead:
//  - Inverse now writes its 8192 real samples CONTIGUOUSLY in-place into its
//    own ws_u slot (old: stride-16B scatter, partial-line cross-XCD writes).
//  - New transpose kernel assembles out[b,k,t,c] (4 coalesced read streams ->
//    float4 contiguous stores), with omega_mean fused into block 0.

#define HALF      8192
#define NH        8192        // half-size FFT length
#define NTHREADS  1024
#define KMODES    4
#define NITERS    20
#define ALPHA_F   2000.0f

typedef __fp16 half2_t __attribute__((ext_vector_type(2)));
typedef float  v2f     __attribute__((ext_vector_type(2)));

__device__ __forceinline__ unsigned bitrev13(unsigned x) { return __brev(x) >> 19; }
__device__ __forceinline__ int pidx(int i) { return i + (i >> 4); }   // LDS pad

__device__ __forceinline__ unsigned pack_h2(float a, float b) {
    half2_t h = __builtin_amdgcn_cvt_pkrtz(a, b);   // v_cvt_pkrtz_f16_f32
    return __builtin_bit_cast(unsigned, h);
}
__device__ __forceinline__ v2f unpack_h2(unsigned u) {
    half2_t h = __builtin_bit_cast(half2_t, u);
    v2f r; r.x = (float)h.x; r.y = (float)h.y; return r;
}

template <int CTRL>
__device__ __forceinline__ float dpp_add_step(float v) {
    int r = __builtin_amdgcn_update_dpp(0, __float_as_int(v), CTRL, 0xf, 0xf, true);
    return v + __int_as_float(r);
}
// Full-wave (64-lane) sum; result valid in lane 63.
__device__ __forceinline__ float wave64_sum(float v) {
    v = dpp_add_step<0x111>(v);   // row_shr:1
    v = dpp_add_step<0x112>(v);   // row_shr:2
    v = dpp_add_step<0x114>(v);   // row_shr:4
    v = dpp_add_step<0x118>(v);   // row_shr:8
    v = dpp_add_step<0x142>(v);   // row_bcast:15
    v = dpp_add_step<0x143>(v);   // row_bcast:31 -> lane63 = wave sum
    return v;
}

__device__ __forceinline__ float2 cmul(float2 a, float wr, float wi) {
    return make_float2(a.x * wr - a.y * wi, a.x * wi + a.y * wr);
}

// One radix-4 pass = two fused radix-2 DIF stages.
template <bool INV>
__device__ __forceinline__ void fft_pass4(float2* A, int tid, int s) {
    const int   log2hh = 11 - 2 * s;
    const int   hh     = 1 << log2hh;                       // h/2
    const float inv2h  = (float)(1 << (2 * s)) * (1.0f / 8192.0f);  // 1/(2h)
    #pragma unroll
    for (int u = 0; u < 2; ++u) {
        int gid = tid + u * NTHREADS;            // group id, 2048 total
        int j   = gid & (hh - 1);
        int blk = gid >> log2hh;
        int i0  = (blk << (log2hh + 2)) + j;     // blk*2h + j
        int i1  = i0 + hh;
        int i2  = i0 + 2 * hh;
        int i3  = i0 + 3 * hh;
        float2 a = A[pidx(i0)], b = A[pidx(i1)];
        float2 c = A[pidx(i2)], d = A[pidx(i3)];
        float rev = (float)j * inv2h;
        float w1r = __builtin_amdgcn_cosf(rev);
        float w1i = INV ?  __builtin_amdgcn_sinf(rev)
                        : -__builtin_amdgcn_sinf(rev);
        float2 ac = make_float2(a.x - c.x, a.y - c.y);
        float2 bd = make_float2(b.x - d.x, b.y - d.y);
        float2 t0 = make_float2(a.x + c.x, a.y + c.y);
        float2 t2 = make_float2(b.x + d.x, b.y + d.y);
        float2 t1 = cmul(ac, w1r, w1i);
        float2 t3;
        if (INV) { // W2 = +i*W1
            t3 = make_float2(-bd.x * w1i - bd.y * w1r, bd.x * w1r - bd.y * w1i);
        } else {   // W2 = -i*W1
            t3 = make_float2( bd.x * w1i + bd.y * w1r, bd.y * w1i - bd.x * w1r);
        }
        float vr = w1r * w1r - w1i * w1i;
        float vi = 2.0f * w1r * w1i;
        float2 s0 = make_float2(t0.x + t2.x, t0.y + t2.y);
        float2 s1 = cmul(make_float2(t0.x - t2.x, t0.y - t2.y), vr, vi);
        float2 s2 = make_float2(t1.x + t3.x, t1.y + t3.y);
        float2 s3 = cmul(make_float2(t1.x - t3.x, t1.y - t3.y), vr, vi);
        A[pidx(i0)] = s0;
        A[pidx(i1)] = s1;
        A[pidx(i2)] = s2;
        A[pidx(i3)] = s3;
    }
}

// Final radix-2 stage (h=1): pairs (2t, 2t+1), twiddle = 1.
__device__ __forceinline__ void fft_last2(float2* A, int tid) {
    #pragma unroll
    for (int u = 0; u < 4; ++u) {
        int t  = tid + u * NTHREADS;
        int i0 = 2 * t, i1 = 2 * t + 1;
        float2 a = A[pidx(i0)], b = A[pidx(i1)];
        A[pidx(i0)] = make_float2(a.x + b.x, a.y + b.y);
        A[pidx(i1)] = make_float2(a.x - b.x, a.y - b.y);
    }
}

// time-domain mirror extension: f[i], i in [0,16384)
__device__ __forceinline__ int mirror_t(int i) {
    if (i < 4096)       return 4095 - i;
    else if (i < 12288) return i - 4096;
    else                return 20479 - i;
}

// ---------------------------------------------------------------------------
// Kernel 1 (== R7): per-channel real-FFT (half-size, radix-4) + 20 VMD iters.
// One block per channel (ch = b*4 + c), 1024 threads, 8 bins/thread.
// ---------------------------------------------------------------------------
__global__ __launch_bounds__(NTHREADS) void vmd_forward_iter(
    const float* __restrict__ x, float2* __restrict__ ws_u,
    float* __restrict__ ws_omega)
{
    __shared__ float2 A[NH + (NH >> 4)];   // padded, ~68 KB
    const int tid = threadIdx.x;
    const int ch  = blockIdx.x;          // b*4 + c
    const int b   = ch >> 2, c = ch & 3;
    const float* xb = x + (size_t)b * 8192 * 4 + c;   // x[b, t, c], stride 4

    // z[m] = f[2m] + i f[2m+1]
    for (int m = tid; m < NH; m += NTHREADS) {
        float re = xb[(size_t)mirror_t(2 * m) * 4];
        float im = xb[(size_t)mirror_t(2 * m + 1) * 4];
        A[pidx(m)] = make_float2(re, im);
    }
    __syncthreads();

    // 8192-pt forward FFT: 6 radix-4 passes + 1 radix-2 stage; bit-reversed out.
    for (int s = 0; s < 6; ++s) {
        fft_pass4<false>(A, tid, s);
        __syncthreads();
    }
    fft_last2(A, tid);
    __syncthreads();

    // Untangle: F[j] = E[j] + w*O[j], w = e^{-2*pi*i*j/16384}, j=0..8191.
    v2f R[8];
    #pragma unroll
    for (int u = 0; u < 8; ++u) {
        int j  = tid + u * NTHREADS;
        float2 z1 = A[pidx((int)bitrev13((unsigned)j))];
        float2 z2 = A[pidx((int)bitrev13((unsigned)((NH - j) & (NH - 1))))];
        float ex = 0.5f * (z1.x + z2.x);
        float ey = 0.5f * (z1.y - z2.y);
        float dx = 0.5f * (z1.x - z2.x);
        float dy = 0.5f * (z1.y + z2.y);
        // O = (dy, -dx)
        float rev = (float)j * (1.0f / 16384.0f);
        float wr = __builtin_amdgcn_cosf(rev);
        float wi = -__builtin_amdgcn_sinf(rev);
        R[u].x = ex + wr * dy + wi * dx;
        R[u].y = ey + wi * dy - wr * dx;
    }
    __syncthreads();   // LDS now reusable as reduction scratch

    unsigned Up[KMODES][8];    // U_k packed as (f16 re, f16 im)
    #pragma unroll
    for (int u = 0; u < 8; ++u)
        #pragma unroll
        for (int k = 0; k < KMODES; ++k) Up[k][u] = 0u;

    const float f0 = (float)tid * (1.0f / 16384.0f);    // fr[u] = f0 + u/16
    float omg[KMODES] = {0.0f, 0.125f, 0.25f, 0.375f};  // 0.5*k/K

    float* red = (float*)A;   // [16 waves][8] partials; [128..135] totals
    const int lane = tid & 63, wid = tid >> 6;

    for (int it = 0; it < NITERS; ++it) {
        float num[KMODES], den[KMODES];
        #pragma unroll
        for (int k = 0; k < KMODES; ++k) {
            float nk = 0.f, dk = 0.f;
            const float ok = omg[k];
            #pragma unroll
            for (int u = 0; u < 8; ++u) {
                float fru = f0 + (float)u * 0.0625f;
                float d   = fru - ok;
                float dnm = fmaf(ALPHA_F * d, d, 1.0f);
                float rcp = __builtin_amdgcn_rcpf(dnm);
                v2f uo  = unpack_h2(Up[k][u]);
                v2f nm  = R[u] + uo;          // v_pk_add_f32
                v2f un  = nm * rcp;           // v_pk_mul_f32 (splat)
                R[u]    = nm - un;            // v_pk_add_f32
                Up[k][u] = pack_h2(un.x, un.y);
                float p = fmaf(un.x, un.x, un.y * un.y);
                nk = fmaf(fru, p, nk);
                dk += p;
            }
            num[k] = nk; den[k] = dk;
        }
        // Stage 1: DPP wave sums, lane63 writes partials.
        #pragma unroll
        for (int m = 0; m < KMODES; ++m) {
            num[m] = wave64_sum(num[m]);
            den[m] = wave64_sum(den[m]);
        }
        if (lane == 63) {
            float4* r4 = (float4*)&red[wid * 8];
            r4[0] = make_float4(num[0], num[1], num[2], num[3]);
            r4[1] = make_float4(den[0], den[1], den[2], den[3]);
        }
        __syncthreads();
        // Stage 2: 8 threads sum the 16 wave-partials of their scalar.
        if (tid < 8) {
            float s = 0.f;
            #pragma unroll
            for (int w = 0; w < 16; ++w) s += red[w * 8 + tid];
            red[128 + tid] = s;
        }
        __syncthreads();
        {
            const float4 nv = *(const float4*)&red[128];
            const float4 dv = *(const float4*)&red[132];
            omg[0] = nv.x * __builtin_amdgcn_rcpf(dv.x);
            omg[1] = nv.y * __builtin_amdgcn_rcpf(dv.y);
            omg[2] = nv.z * __builtin_amdgcn_rcpf(dv.z);
            omg[3] = nv.w * __builtin_amdgcn_rcpf(dv.w);
        }
        // next iter writes red[0..127] (disjoint from 128..135) — safe.
    }

    // Write final positive-half u_hat and omega.
    #pragma unroll
    for (int k = 0; k < KMODES; ++k) {
        float2* dst = ws_u + (size_t)(ch * KMODES + k) * HALF;
        #pragma unroll
        for (int u = 0; u < 8; ++u) {
            v2f uv = unpack_h2(Up[k][u]);
            dst[tid + u * NTHREADS] = make_float2(uv.x, uv.y);
        }
    }
    if (tid < KMODES) ws_omega[ch * KMODES + tid] = omg[tid];
}

// ---------------------------------------------------------------------------
// Kernel 2: per (channel,mode) half-size real iFFT.
// Writes the middle 8192 real samples CONTIGUOUSLY in-place into the first
// half of this block's own ws_u slot (slot fully consumed into LDS before the
// first barrier, so the overwrite is safe). Float layout of slot after this
// kernel: u_tmp[bid*16384 + t] = u(t), t in [0,8192).
// ---------------------------------------------------------------------------
__global__ __launch_bounds__(NTHREADS) void vmd_inverse(
    float2* __restrict__ ws_u)
{
    __shared__ float2 A[NH + (NH >> 4)];
    const int tid = threadIdx.x;
    const int bid = blockIdx.x;             // ch*4 + k
    float2* pos = ws_u + (size_t)bid * HALF;

    for (int j = tid; j < NH; j += NTHREADS) {
        float2 gj, gh;
        if (j == 0) {
            float2 p0 = pos[0], pl = pos[HALF - 1];
            gj = make_float2(p0.x, -p0.y);       // G[0]    = conj(p[0])
            gh = make_float2(pl.x, -pl.y);       // G[8192] = conj(p[8191])
        } else {
            gj = pos[j];                          // G[j]
            float2 q = pos[HALF - j];             // G[j+8192] = conj(p[8192-j])
            gh = make_float2(q.x, -q.y);
        }
        float ex = 0.5f * (gj.x + gh.x), ey = 0.5f * (gj.y + gh.y);
        float dx = 0.5f * (gj.x - gh.x), dy = 0.5f * (gj.y - gh.y);
        float rev = (float)j * (1.0f / 16384.0f);
        float wr = __builtin_amdgcn_cosf(rev);
        float wi = __builtin_amdgcn_sinf(rev);    // e^{+2*pi*i*rev}
        float ox = dx * wr - dy * wi;
        float oy = dx * wi + dy * wr;
        A[pidx(j)] = make_float2(ex - oy, ey + ox);   // Z = E + i*O
    }
    __syncthreads();

    // 8192-pt inverse FFT: 6 radix-4 passes + 1 radix-2 stage; bit-reversed out.
    for (int s = 0; s < 6; ++s) {
        fft_pass4<true>(A, tid, s);
        __syncthreads();
    }
    fft_last2(A, tid);
    __syncthreads();

    // Keep n in [4096,12288): m in [2048,6144). x[2m]=Re z, x[2m+1]=Im z.
    // Contiguous in-place store: float2 slot index (m-2048) <=> floats t0,t0+1.
    for (int m = 2048 + tid; m < 6144; m += NTHREADS) {
        float2 z = A[pidx((int)bitrev13((unsigned)m))];
        pos[m - 2048] = make_float2(z.x * (1.0f / 8192.0f),
                                    z.y * (1.0f / 8192.0f));
    }
}

// ---------------------------------------------------------------------------
// Kernel 3: assemble out[b,k,t,c] from u_tmp (4 coalesced read streams ->
// contiguous float4 stores) + omega mean fused into block 0.
// u_tmp float layout: u_tmp[((b*4+c)*4+k)*16384 + t].
// ---------------------------------------------------------------------------
__global__ __launch_bounds__(NTHREADS) void vmd_assemble(
    const float* __restrict__ u_tmp, const float* __restrict__ ws_omega,
    float* __restrict__ out)
{
    int gid = blockIdx.x * NTHREADS + threadIdx.x;   // (b*4+k)*8192 + t
    int t  = gid & 8191;
    int bk = gid >> 13;
    int b  = bk >> 2, k = bk & 3;
    float4 v;
    v.x = u_tmp[(size_t)(((b * 4 + 0) * 4 + k)) * 16384 + t];
    v.y = u_tmp[(size_t)(((b * 4 + 1) * 4 + k)) * 16384 + t];
    v.z = u_tmp[(size_t)(((b * 4 + 2) * 4 + k)) * 16384 + t];
    v.w = u_tmp[(size_t)(((b * 4 + 3) * 4 + k)) * 16384 + t];
    ((float4*)out)[gid] = v;

    if (blockIdx.x == 0 && threadIdx.x < 64) {
        int i = threadIdx.x;                 // b*4 + k
        int bb = i >> 2, kk = i & 3;
        float s = 0.f;
        #pragma unroll
        for (int c = 0; c < 4; ++c) s += ws_omega[(bb * 4 + c) * 4 + kk];
        out[2097152 + i] = 0.25f * s;
    }
}

extern "C" void kernel_launch(void* const* d_in, const int* in_sizes, int n_in,
                              void* d_out, int out_size, void* d_ws, size_t ws_size,
                              hipStream_t stream)
{
    (void)in_sizes; (void)n_in; (void)out_size; (void)ws_size;
    const float* x = (const float*)d_in[0];
    float* out = (float*)d_out;

    float2* ws_u     = (float2*)d_ws;  // 64 ch * 4 modes * 8192 float2 = 16 MB
    float*  ws_omega = (float*)((char*)d_ws + (size_t)64 * 4 * HALF * sizeof(float2));

    vmd_forward_iter<<<64, NTHREADS, 0, stream>>>(x, ws_u, ws_omega);
    vmd_inverse<<<256, NTHREADS, 0, stream>>>(ws_u);
    vmd_assemble<<<512, NTHREADS, 0, stream>>>((const float*)ws_u, ws_omega, out);
}